// Round 1
// baseline (548.239 us; speedup 1.0000x reference)
//
#include <hip/hip_runtime.h>

#define G16 16
#define CHW 200704            // C*H*W = 64*56*56
#define J4 (CHW / 4)          // 50176 float4 chunks per (n,g) slab
#define NBATCH 16             // N
#define NCHUNK (NBATCH * J4)  // 802816 total float4 chunks per group-slice
#define NPAIR 136             // 16*17/2 triangular Gram entries
#define NVAL (NPAIR + G16)    // 152 reduced values per block
#define PSTRIDE 160           // padded partial stride
#define M_ELEMS 3211264.0f    // N*C*H*W
#define EPSV 1e-5f

// Pass 1: per-block partial Gram (136 triangular entries) + per-group sums.
__global__ __launch_bounds__(256, 2) void gram_k(const float* __restrict__ x,
                                                 float* __restrict__ partials) {
    float acc[NPAIR];
    float sums[G16];
#pragma unroll
    for (int i = 0; i < NPAIR; ++i) acc[i] = 0.f;
#pragma unroll
    for (int g = 0; g < G16; ++g) sums[g] = 0.f;

    const int tid = blockIdx.x * blockDim.x + threadIdx.x;
    const int stride = gridDim.x * blockDim.x;
    for (int c = tid; c < NCHUNK; c += stride) {
        const int n = c / J4;
        const int j4 = c - n * J4;
        const float* bp = x + (size_t)n * (G16 * CHW) + (size_t)j4 * 4;
        float4 v[G16];
#pragma unroll
        for (int g = 0; g < G16; ++g)
            v[g] = *reinterpret_cast<const float4*>(bp + (size_t)g * CHW);
#pragma unroll
        for (int g1 = 0; g1 < G16; ++g1) {
            sums[g1] += (v[g1].x + v[g1].y) + (v[g1].z + v[g1].w);
#pragma unroll
            for (int g2 = 0; g2 <= g1; ++g2) {
                const int p = g1 * (g1 + 1) / 2 + g2;
                acc[p] = fmaf(v[g1].x, v[g2].x,
                         fmaf(v[g1].y, v[g2].y,
                         fmaf(v[g1].z, v[g2].z,
                         fmaf(v[g1].w, v[g2].w, acc[p]))));
            }
        }
    }

    // wave butterfly reduce (64 lanes), then cross-wave via LDS
    __shared__ float red[4][NVAL];
    const int lane = threadIdx.x & 63;
    const int wave = threadIdx.x >> 6;
#pragma unroll
    for (int i = 0; i < NPAIR; ++i) {
        float v = acc[i];
#pragma unroll
        for (int o = 32; o > 0; o >>= 1) v += __shfl_xor(v, o, 64);
        if (lane == 0) red[wave][i] = v;
    }
#pragma unroll
    for (int g = 0; g < G16; ++g) {
        float v = sums[g];
#pragma unroll
        for (int o = 32; o > 0; o >>= 1) v += __shfl_xor(v, o, 64);
        if (lane == 0) red[wave][NPAIR + g] = v;
    }
    __syncthreads();
    if (threadIdx.x < NVAL) {
        const float t = red[0][threadIdx.x] + red[1][threadIdx.x] +
                        red[2][threadIdx.x] + red[3][threadIdx.x];
        partials[(size_t)blockIdx.x * PSTRIDE + threadIdx.x] = t;
    }
}

// Pass 2: reduce partials, build Sigma, Cholesky, invert L, write wm (16x16, zeros above diag).
__global__ void solve_k(const float* __restrict__ partials, int nblk,
                        float* __restrict__ wm) {
    __shared__ float sm[NVAL];
    __shared__ float Sig[G16][G16];
    __shared__ float L[G16][G16];
    __shared__ float W[G16][G16];
    const int t = threadIdx.x;
    if (t < NVAL) {
        float a = 0.f;
        for (int b = 0; b < nblk; ++b) a += partials[(size_t)b * PSTRIDE + t];
        sm[t] = a;
    }
    __syncthreads();
    if (t == 0) {
        const float inv_m = 1.0f / M_ELEMS;
        float mu[G16];
#pragma unroll
        for (int g = 0; g < G16; ++g) mu[g] = sm[NPAIR + g] * inv_m;
        float tr = 0.f;
#pragma unroll
        for (int g1 = 0; g1 < G16; ++g1) {
#pragma unroll
            for (int g2 = 0; g2 <= g1; ++g2) {
                float v = sm[g1 * (g1 + 1) / 2 + g2] * inv_m - mu[g1] * mu[g2];
                if (g1 == g2) { v += EPSV; tr += v; }
                Sig[g1][g2] = v;
                Sig[g2][g1] = v;
            }
        }
        const float rtr = 1.0f / tr;
        // Cholesky of Sig * rtr (lower L)
        for (int j = 0; j < G16; ++j) {
            float s = Sig[j][j] * rtr;
            for (int k = 0; k < j; ++k) s -= L[j][k] * L[j][k];
            const float d = sqrtf(s);
            L[j][j] = d;
            const float invd = 1.0f / d;
            for (int i = j + 1; i < G16; ++i) {
                float s2 = Sig[i][j] * rtr;
                for (int k = 0; k < j; ++k) s2 -= L[i][k] * L[j][k];
                L[i][j] = s2 * invd;
            }
        }
        // W = L^{-1} (lower triangular)
        for (int j = 0; j < G16; ++j) {
            W[j][j] = 1.0f / L[j][j];
            for (int i = j + 1; i < G16; ++i) {
                float s2 = 0.f;
                for (int k = j; k < i; ++k) s2 += L[i][k] * W[k][j];
                W[i][j] = -s2 / L[i][i];
            }
        }
        for (int i = 0; i < G16; ++i)
            for (int j = 0; j < G16; ++j)
                wm[i * G16 + j] = (j <= i) ? W[i][j] : 0.f;
    }
}

// Pass 3: out[g,:] = sum_{g2<=g} wm[g][g2] * x[g2,:]
__global__ __launch_bounds__(256) void apply_k(const float* __restrict__ x,
                                               const float* __restrict__ wm,
                                               float* __restrict__ out) {
    __shared__ float w[G16 * G16];
    if (threadIdx.x < G16 * G16) w[threadIdx.x] = wm[threadIdx.x];
    __syncthreads();
    const int tid = blockIdx.x * blockDim.x + threadIdx.x;
    const int stride = gridDim.x * blockDim.x;
    for (int c = tid; c < NCHUNK; c += stride) {
        const int n = c / J4;
        const int j4 = c - n * J4;
        const size_t base = (size_t)n * (G16 * CHW) + (size_t)j4 * 4;
        float4 v[G16];
#pragma unroll
        for (int g = 0; g < G16; ++g)
            v[g] = *reinterpret_cast<const float4*>(x + base + (size_t)g * CHW);
#pragma unroll
        for (int g = 0; g < G16; ++g) {
            float4 o = make_float4(0.f, 0.f, 0.f, 0.f);
#pragma unroll
            for (int g2 = 0; g2 <= g; ++g2) {
                const float wv = w[g * G16 + g2];
                o.x = fmaf(wv, v[g2].x, o.x);
                o.y = fmaf(wv, v[g2].y, o.y);
                o.z = fmaf(wv, v[g2].z, o.z);
                o.w = fmaf(wv, v[g2].w, o.w);
            }
            *reinterpret_cast<float4*>(out + base + (size_t)g * CHW) = o;
        }
    }
}

extern "C" void kernel_launch(void* const* d_in, const int* in_sizes, int n_in,
                              void* d_out, int out_size, void* d_ws, size_t ws_size,
                              hipStream_t stream) {
    const float* x = (const float*)d_in[0];
    float* out = (float*)d_out;
    float* wm = (float*)d_ws;                 // first 256 floats
    float* partials = (float*)d_ws + 256;

    int nblk = 1024;
    const size_t avail = (ws_size / 4 > 256) ? ((ws_size / 4 - 256) / PSTRIDE) : 1;
    if ((size_t)nblk > avail) nblk = (int)avail;
    if (nblk < 1) nblk = 1;

    gram_k<<<nblk, 256, 0, stream>>>(x, partials);
    solve_k<<<1, 256, 0, stream>>>(partials, nblk, wm);
    apply_k<<<2048, 256, 0, stream>>>(x, wm, out);
}

// Round 2
// 526.176 us; speedup vs baseline: 1.0419x; 1.0419x over previous
//
#include <hip/hip_runtime.h>

#define G16 16
#define CHW 200704            // C*H*W = 64*56*56
#define J4 (CHW / 4)          // 50176 float4 chunks per (n,g) slab
#define NBATCH 16             // N
#define NCHUNK (NBATCH * J4)  // 802816 total float4 chunks
#define NPAIR 136             // 16*17/2 triangular Gram entries
#define NVAL (NPAIR + G16)    // 152 reduced values per block
#define NBLK_DEF 784          // 784 blocks * 256 thr * 4 chunks = NCHUNK exactly
#define M_ELEMS 3211264.0f    // N*C*H*W
#define EPSV 1e-5f

using f4 = __attribute__((ext_vector_type(4))) float;

// Pass 1: per-block partial Gram (136 triangular entries) + per-group sums.
// Partials layout TRANSPOSED: partials[v * nblk + b] for coalesced reduce.
__global__ __launch_bounds__(256, 2) void gram_k(const float* __restrict__ x,
                                                 float* __restrict__ partials,
                                                 int nblk) {
    float acc[NPAIR];
    float sums[G16];
#pragma unroll
    for (int i = 0; i < NPAIR; ++i) acc[i] = 0.f;
#pragma unroll
    for (int g = 0; g < G16; ++g) sums[g] = 0.f;

    const int tid = blockIdx.x * blockDim.x + threadIdx.x;
    const int stride = gridDim.x * blockDim.x;
    for (int c = tid; c < NCHUNK; c += stride) {
        const int n = c / J4;
        const int j4 = c - n * J4;
        const float* bp = x + (size_t)n * (G16 * CHW) + (size_t)j4 * 4;
        f4 v[G16];
#pragma unroll
        for (int g = 0; g < G16; ++g)
            v[g] = *reinterpret_cast<const f4*>(bp + (size_t)g * CHW);
#pragma unroll
        for (int g1 = 0; g1 < G16; ++g1) {
            sums[g1] += (v[g1].x + v[g1].y) + (v[g1].z + v[g1].w);
#pragma unroll
            for (int g2 = 0; g2 <= g1; ++g2) {
                const int p = g1 * (g1 + 1) / 2 + g2;
                acc[p] = fmaf(v[g1].x, v[g2].x,
                         fmaf(v[g1].y, v[g2].y,
                         fmaf(v[g1].z, v[g2].z,
                         fmaf(v[g1].w, v[g2].w, acc[p]))));
            }
        }
    }

    __shared__ float red[4][NVAL];
    const int lane = threadIdx.x & 63;
    const int wave = threadIdx.x >> 6;
#pragma unroll
    for (int i = 0; i < NPAIR; ++i) {
        float v = acc[i];
#pragma unroll
        for (int o = 32; o > 0; o >>= 1) v += __shfl_xor(v, o, 64);
        if (lane == 0) red[wave][i] = v;
    }
#pragma unroll
    for (int g = 0; g < G16; ++g) {
        float v = sums[g];
#pragma unroll
        for (int o = 32; o > 0; o >>= 1) v += __shfl_xor(v, o, 64);
        if (lane == 0) red[wave][NPAIR + g] = v;
    }
    __syncthreads();
    if (threadIdx.x < NVAL) {
        const float t = red[0][threadIdx.x] + red[1][threadIdx.x] +
                        red[2][threadIdx.x] + red[3][threadIdx.x];
        partials[(size_t)threadIdx.x * nblk + blockIdx.x] = t;
    }
}

// Pass 2 (one block, 1024 thr): parallel partial-reduce, then wave-parallel
// register Cholesky + triangular inverse on wave 0 (lane i = row i).
__global__ __launch_bounds__(1024) void solve_k(const float* __restrict__ partials,
                                                int nblk, float* __restrict__ wm) {
    __shared__ float sm[NVAL];
    const int lane = threadIdx.x & 63;
    const int wave = threadIdx.x >> 6;
    for (int v = wave; v < NVAL; v += 16) {
        float a = 0.f;
        for (int b = lane; b < nblk; b += 64)
            a += partials[(size_t)v * nblk + b];
#pragma unroll
        for (int o = 32; o > 0; o >>= 1) a += __shfl_xor(a, o, 64);
        if (lane == 0) sm[v] = a;
    }
    __syncthreads();
    if (wave != 0) return;

    const float inv_m = 1.0f / M_ELEMS;
    const int i = lane;  // row index (valid for i<16)
    const float mu_i = (i < G16) ? sm[NPAIR + i] * inv_m : 0.f;

    // trace of Sigma_raw + eps
    float di = 0.f;
    if (i < G16) di = sm[i * (i + 1) / 2 + i] * inv_m - mu_i * mu_i + EPSV;
    float tr = di;
#pragma unroll
    for (int o = 32; o > 0; o >>= 1) tr += __shfl_xor(tr, o, 64);
    const float rtr = 1.0f / tr;

    // row i of Sigma_N
    float A[G16];
#pragma unroll
    for (int j = 0; j < G16; ++j) {
        const float mu_j = sm[NPAIR + j] * inv_m;
        const int idx = (i >= j) ? (i * (i + 1) / 2 + j) : (j * (j + 1) / 2 + i);
        float v = (i < G16) ? sm[idx] * inv_m : 0.f;
        v = v - mu_i * mu_j + ((i == j) ? EPSV : 0.f);
        A[j] = v * rtr;
    }

    // Cholesky: lane i holds row i of L
    float Lr[G16];
    float dinv = 0.f;  // 1/L[i][i] on lane i
#pragma unroll
    for (int j = 0; j < G16; ++j) {
        float s = A[j];
#pragma unroll
        for (int k = 0; k < j; ++k)
            s -= Lr[k] * __shfl(Lr[k], j, 64);
        const float djj = __shfl(s, j, 64);
        const float d = sqrtf(djj);
        const float inv = 1.0f / d;
        float lij = (i == j) ? d : s * inv;
        if (i < j) lij = 0.f;
        Lr[j] = lij;
        if (i == j) dinv = inv;
    }

    // W = L^{-1}: lane j holds column j; forward substitution over rows r
    float Wc[G16];
#pragma unroll
    for (int r = 0; r < G16; ++r) {
        float s = (lane == r) ? 1.f : 0.f;
#pragma unroll
        for (int k = 0; k < r; ++k)
            s -= __shfl(Lr[k], r, 64) * Wc[k];
        Wc[r] = s * __shfl(dinv, r, 64);
    }
    // lane j writes column j (Wc[r] == 0 for r < j by construction)
    if (lane < G16) {
#pragma unroll
        for (int r = 0; r < G16; ++r)
            wm[r * G16 + lane] = Wc[r];
    }
}

// Pass 3: out[g,:] = sum_{g2<=g} wm[g][g2] * x[g2,:]  (nontemporal stores)
__global__ __launch_bounds__(256) void apply_k(const float* __restrict__ x,
                                               const float* __restrict__ wm,
                                               float* __restrict__ out) {
    __shared__ float w[G16 * G16];
    if (threadIdx.x < G16 * G16) w[threadIdx.x] = wm[threadIdx.x];
    __syncthreads();
    const int tid = blockIdx.x * blockDim.x + threadIdx.x;
    const int stride = gridDim.x * blockDim.x;
    for (int c = tid; c < NCHUNK; c += stride) {
        const int n = c / J4;
        const int j4 = c - n * J4;
        const size_t base = (size_t)n * (G16 * CHW) + (size_t)j4 * 4;
        f4 v[G16];
#pragma unroll
        for (int g = 0; g < G16; ++g)
            v[g] = *reinterpret_cast<const f4*>(x + base + (size_t)g * CHW);
#pragma unroll
        for (int g = 0; g < G16; ++g) {
            f4 o = {0.f, 0.f, 0.f, 0.f};
#pragma unroll
            for (int g2 = 0; g2 <= g; ++g2) {
                const float wv = w[g * G16 + g2];
                o.x = fmaf(wv, v[g2].x, o.x);
                o.y = fmaf(wv, v[g2].y, o.y);
                o.z = fmaf(wv, v[g2].z, o.z);
                o.w = fmaf(wv, v[g2].w, o.w);
            }
            __builtin_nontemporal_store(o, reinterpret_cast<f4*>(out + base + (size_t)g * CHW));
        }
    }
}

extern "C" void kernel_launch(void* const* d_in, const int* in_sizes, int n_in,
                              void* d_out, int out_size, void* d_ws, size_t ws_size,
                              hipStream_t stream) {
    const float* x = (const float*)d_in[0];
    float* out = (float*)d_out;
    float* wm = (float*)d_ws;                 // first 256 floats
    float* partials = (float*)d_ws + 256;

    int nblk = NBLK_DEF;
    const size_t avail = (ws_size / 4 > 256) ? ((ws_size / 4 - 256) / NVAL) : 1;
    if ((size_t)nblk > avail) nblk = (int)avail;
    if (nblk < 1) nblk = 1;

    gram_k<<<nblk, 256, 0, stream>>>(x, partials, nblk);
    solve_k<<<1, 1024, 0, stream>>>(partials, nblk, wm);
    apply_k<<<2048, 256, 0, stream>>>(x, wm, out);
}

// Round 3
// 174.167 us; speedup vs baseline: 3.1478x; 3.0211x over previous
//
#include <hip/hip_runtime.h>

#define G16 16
#define CHW 200704            // C*H*W = 64*56*56
#define J4 (CHW / 4)          // 50176 float4 chunks per (n,g) slab
#define NBATCH 16             // N
#define NCHUNK (NBATCH * J4)  // 802816 total float4 chunks
#define NPAIR 136             // 16*17/2 triangular Gram entries
#define NVAL (NPAIR + G16)    // 152 reduced values
#define NBLK 784              // gram blocks: NBLK*64 == J4 exactly
#define M_ELEMS 3211264.0f    // N*C*H*W
#define EPSV 1e-5f

using f4 = __attribute__((ext_vector_type(4))) float;

__device__ __forceinline__ float dot4(const f4 a, const f4 b, float acc) {
    return fmaf(a.x, b.x, fmaf(a.y, b.y, fmaf(a.z, b.z, fmaf(a.w, b.w, acc))));
}
__device__ __forceinline__ float wred(float v) {
#pragma unroll
    for (int o = 32; o > 0; o >>= 1) v += __shfl_xor(v, o, 64);
    return v;
}

// Pass 1: pair-split Gram. Each block owns 64 consecutive f4-positions per
// batch slab; wave w computes its pair subset over those positions.
//  wave0: tri pairs within groups 0..7  (36) + sums 0..7
//  wave1: tri pairs within groups 8..15 (36) + sums 8..15
//  wave2: rect pairs g1 in 8..15 x g2 in 0..3 (32)
//  wave3: rect pairs g1 in 8..15 x g2 in 4..7 (32)
__global__ __launch_bounds__(256, 4) void gram_k(const float* __restrict__ x,
                                                 float* __restrict__ partials) {
    const int lane = threadIdx.x & 63;
    const int wv = threadIdx.x >> 6;
    const float* base = x + (size_t)(blockIdx.x * 64 + lane) * 4;
    __shared__ float red[NVAL];

    if (wv < 2) {
        const int GB = wv * 8;
        float acc[36], sums[8];
#pragma unroll
        for (int i = 0; i < 36; ++i) acc[i] = 0.f;
#pragma unroll
        for (int g = 0; g < 8; ++g) sums[g] = 0.f;
#pragma unroll 1
        for (int n = 0; n < NBATCH; ++n) {
            const float* bp = base + (size_t)n * (G16 * CHW);
            f4 v[8];
#pragma unroll
            for (int g = 0; g < 8; ++g)
                v[g] = *reinterpret_cast<const f4*>(bp + (size_t)(GB + g) * CHW);
#pragma unroll
            for (int g1 = 0; g1 < 8; ++g1) {
                sums[g1] += (v[g1].x + v[g1].y) + (v[g1].z + v[g1].w);
#pragma unroll
                for (int g2 = 0; g2 <= g1; ++g2)
                    acc[g1 * (g1 + 1) / 2 + g2] =
                        dot4(v[g1], v[g2], acc[g1 * (g1 + 1) / 2 + g2]);
            }
        }
#pragma unroll
        for (int g1 = 0; g1 < 8; ++g1)
#pragma unroll
            for (int g2 = 0; g2 <= g1; ++g2) {
                const float s = wred(acc[g1 * (g1 + 1) / 2 + g2]);
                if (lane == 0) {
                    const int G1 = GB + g1, G2 = GB + g2;
                    red[G1 * (G1 + 1) / 2 + G2] = s;
                }
            }
#pragma unroll
        for (int g = 0; g < 8; ++g) {
            const float s = wred(sums[g]);
            if (lane == 0) red[NPAIR + GB + g] = s;
        }
    } else {
        const int G2B = (wv - 2) * 4;
        float acc[32];
#pragma unroll
        for (int i = 0; i < 32; ++i) acc[i] = 0.f;
#pragma unroll 1
        for (int n = 0; n < NBATCH; ++n) {
            const float* bp = base + (size_t)n * (G16 * CHW);
            f4 v1[8], v2[4];
#pragma unroll
            for (int a = 0; a < 8; ++a)
                v1[a] = *reinterpret_cast<const f4*>(bp + (size_t)(8 + a) * CHW);
#pragma unroll
            for (int b = 0; b < 4; ++b)
                v2[b] = *reinterpret_cast<const f4*>(bp + (size_t)(G2B + b) * CHW);
#pragma unroll
            for (int a = 0; a < 8; ++a)
#pragma unroll
                for (int b = 0; b < 4; ++b)
                    acc[a * 4 + b] = dot4(v1[a], v2[b], acc[a * 4 + b]);
        }
#pragma unroll
        for (int a = 0; a < 8; ++a)
#pragma unroll
            for (int b = 0; b < 4; ++b) {
                const float s = wred(acc[a * 4 + b]);
                if (lane == 0) {
                    const int G1 = 8 + a, G2 = G2B + b;
                    red[G1 * (G1 + 1) / 2 + G2] = s;
                }
            }
    }
    __syncthreads();
    if (threadIdx.x < NVAL)
        partials[(size_t)threadIdx.x * NBLK + blockIdx.x] = red[threadIdx.x];
}

// Pass 2 (one block, 1024 thr): parallel partial-reduce, then wave-parallel
// register Cholesky + triangular inverse on wave 0 (lane i = row i).
__global__ __launch_bounds__(1024) void solve_k(const float* __restrict__ partials,
                                                int nblk, float* __restrict__ wm) {
    __shared__ float sm[NVAL];
    const int lane = threadIdx.x & 63;
    const int wave = threadIdx.x >> 6;
    for (int v = wave; v < NVAL; v += 16) {
        float a = 0.f;
        for (int b = lane; b < nblk; b += 64)
            a += partials[(size_t)v * nblk + b];
#pragma unroll
        for (int o = 32; o > 0; o >>= 1) a += __shfl_xor(a, o, 64);
        if (lane == 0) sm[v] = a;
    }
    __syncthreads();
    if (wave != 0) return;

    const float inv_m = 1.0f / M_ELEMS;
    const int i = lane;  // row index (valid for i<16)
    const float mu_i = (i < G16) ? sm[NPAIR + i] * inv_m : 0.f;

    float di = 0.f;
    if (i < G16) di = sm[i * (i + 1) / 2 + i] * inv_m - mu_i * mu_i + EPSV;
    float tr = di;
#pragma unroll
    for (int o = 32; o > 0; o >>= 1) tr += __shfl_xor(tr, o, 64);
    const float rtr = 1.0f / tr;

    float A[G16];
#pragma unroll
    for (int j = 0; j < G16; ++j) {
        const float mu_j = sm[NPAIR + j] * inv_m;
        const int idx = (i >= j) ? (i * (i + 1) / 2 + j) : (j * (j + 1) / 2 + i);
        float v = (i < G16) ? sm[idx] * inv_m : 0.f;
        v = v - mu_i * mu_j + ((i == j) ? EPSV : 0.f);
        A[j] = v * rtr;
    }

    float Lr[G16];
    float dinv = 0.f;
#pragma unroll
    for (int j = 0; j < G16; ++j) {
        float s = A[j];
#pragma unroll
        for (int k = 0; k < j; ++k)
            s -= Lr[k] * __shfl(Lr[k], j, 64);
        const float djj = __shfl(s, j, 64);
        const float d = sqrtf(djj);
        const float inv = 1.0f / d;
        float lij = (i == j) ? d : s * inv;
        if (i < j) lij = 0.f;
        Lr[j] = lij;
        if (i == j) dinv = inv;
    }

    float Wc[G16];
#pragma unroll
    for (int r = 0; r < G16; ++r) {
        float s = (lane == r) ? 1.f : 0.f;
#pragma unroll
        for (int k = 0; k < r; ++k)
            s -= __shfl(Lr[k], r, 64) * Wc[k];
        Wc[r] = s * __shfl(dinv, r, 64);
    }
    if (lane < G16) {
#pragma unroll
        for (int r = 0; r < G16; ++r)
            wm[r * G16 + lane] = Wc[r];
    }
}

// Pass 3: out[g,:] = sum_{g2<=g} wm[g][g2] * x[g2,:]
// Exactly ONE float4 chunk per thread (grid*block == NCHUNK): no loop, no
// iteration interleaving, ~80 VGPR, no spills. NT stores keep `out` from
// evicting L3-resident x.
__global__ __launch_bounds__(256, 4) void apply_k(const float* __restrict__ x,
                                                  const float* __restrict__ wm,
                                                  float* __restrict__ out) {
    __shared__ float w[G16 * G16];
    if (threadIdx.x < G16 * G16) w[threadIdx.x] = wm[threadIdx.x];
    __syncthreads();
    const int c = blockIdx.x * 256 + threadIdx.x;
    const int n = c / J4;
    const int j4 = c - n * J4;
    const size_t base = (size_t)n * (G16 * CHW) + (size_t)j4 * 4;
    f4 v[G16];
#pragma unroll
    for (int g = 0; g < G16; ++g)
        v[g] = *reinterpret_cast<const f4*>(x + base + (size_t)g * CHW);
#pragma unroll
    for (int g = 0; g < G16; ++g) {
        f4 o = {0.f, 0.f, 0.f, 0.f};
#pragma unroll
        for (int g2 = 0; g2 <= g; ++g2) {
            const float wv = w[g * G16 + g2];
            o.x = fmaf(wv, v[g2].x, o.x);
            o.y = fmaf(wv, v[g2].y, o.y);
            o.z = fmaf(wv, v[g2].z, o.z);
            o.w = fmaf(wv, v[g2].w, o.w);
        }
        __builtin_nontemporal_store(o, reinterpret_cast<f4*>(out + base + (size_t)g * CHW));
    }
}

extern "C" void kernel_launch(void* const* d_in, const int* in_sizes, int n_in,
                              void* d_out, int out_size, void* d_ws, size_t ws_size,
                              hipStream_t stream) {
    const float* x = (const float*)d_in[0];
    float* out = (float*)d_out;
    float* wm = (float*)d_ws;                 // first 256 floats
    float* partials = (float*)d_ws + 256;     // NVAL * NBLK floats (~466 KB)

    gram_k<<<NBLK, 256, 0, stream>>>(x, partials);
    solve_k<<<1, 1024, 0, stream>>>(partials, NBLK, wm);
    apply_k<<<NCHUNK / 256, 256, 0, stream>>>(x, wm, out);
}

// Round 4
// 162.038 us; speedup vs baseline: 3.3834x; 1.0749x over previous
//
#include <hip/hip_runtime.h>

#define G16 16
#define CHW 200704            // C*H*W = 64*56*56
#define J4 (CHW / 4)          // 50176 float4 chunks per (n,g) slab
#define NBATCH 16             // N
#define NCHUNK (NBATCH * J4)  // 802816 total float4 chunks
#define NPAIR 136             // 16*17/2 triangular Gram entries
#define NVAL (NPAIR + G16)    // 152 reduced values
#define NPOSBLK 784           // position-blocks per batch slab: 784*64 == J4
#define NTILES (NBATCH * NPOSBLK)  // 12544 (n, posblk) tiles
#define NBLK_MAX 1024         // 4 blocks/CU * 256 CU — full residency
#define M_ELEMS 3211264.0f    // N*C*H*W
#define EPSV 1e-5f

using f4 = __attribute__((ext_vector_type(4))) float;

__device__ __forceinline__ float dot4(const f4 a, const f4 b, float acc) {
    return fmaf(a.x, b.x, fmaf(a.y, b.y, fmaf(a.z, b.z, fmaf(a.w, b.w, acc))));
}
__device__ __forceinline__ float wred(float v) {
#pragma unroll
    for (int o = 32; o > 0; o >>= 1) v += __shfl_xor(v, o, 64);
    return v;
}

// Pass 1: pair-split Gram, grid-stride over (n, posblk) tiles so all 256 CUs
// stay busy to the end (784 long blocks only occupied 196 CUs).
//  wave0: tri pairs within groups 0..7  (36) + sums 0..7
//  wave1: tri pairs within groups 8..15 (36) + sums 8..15
//  wave2: rect pairs g1 in 8..15 x g2 in 0..3 (32)
//  wave3: rect pairs g1 in 8..15 x g2 in 4..7 (32)
__global__ __launch_bounds__(256, 4) void gram_k(const float* __restrict__ x,
                                                 float* __restrict__ partials,
                                                 int nblk) {
    const int lane = threadIdx.x & 63;
    const int wv = threadIdx.x >> 6;
    __shared__ float red[NVAL];

    if (wv < 2) {
        const int GB = wv * 8;
        float acc[36], sums[8];
#pragma unroll
        for (int i = 0; i < 36; ++i) acc[i] = 0.f;
#pragma unroll
        for (int g = 0; g < 8; ++g) sums[g] = 0.f;
#pragma unroll 1
        for (int t = blockIdx.x; t < NTILES; t += nblk) {
            const int n = t / NPOSBLK;
            const int pb = t - n * NPOSBLK;
            const float* bp = x + (size_t)n * (G16 * CHW) + (size_t)(pb * 64 + lane) * 4;
            f4 v[8];
#pragma unroll
            for (int g = 0; g < 8; ++g)
                v[g] = *reinterpret_cast<const f4*>(bp + (size_t)(GB + g) * CHW);
#pragma unroll
            for (int g1 = 0; g1 < 8; ++g1) {
                sums[g1] += (v[g1].x + v[g1].y) + (v[g1].z + v[g1].w);
#pragma unroll
                for (int g2 = 0; g2 <= g1; ++g2)
                    acc[g1 * (g1 + 1) / 2 + g2] =
                        dot4(v[g1], v[g2], acc[g1 * (g1 + 1) / 2 + g2]);
            }
        }
#pragma unroll
        for (int g1 = 0; g1 < 8; ++g1)
#pragma unroll
            for (int g2 = 0; g2 <= g1; ++g2) {
                const float s = wred(acc[g1 * (g1 + 1) / 2 + g2]);
                if (lane == 0) {
                    const int G1 = GB + g1, G2 = GB + g2;
                    red[G1 * (G1 + 1) / 2 + G2] = s;
                }
            }
#pragma unroll
        for (int g = 0; g < 8; ++g) {
            const float s = wred(sums[g]);
            if (lane == 0) red[NPAIR + GB + g] = s;
        }
    } else {
        const int G2B = (wv - 2) * 4;
        float acc[32];
#pragma unroll
        for (int i = 0; i < 32; ++i) acc[i] = 0.f;
#pragma unroll 1
        for (int t = blockIdx.x; t < NTILES; t += nblk) {
            const int n = t / NPOSBLK;
            const int pb = t - n * NPOSBLK;
            const float* bp = x + (size_t)n * (G16 * CHW) + (size_t)(pb * 64 + lane) * 4;
            f4 v1[8], v2[4];
#pragma unroll
            for (int a = 0; a < 8; ++a)
                v1[a] = *reinterpret_cast<const f4*>(bp + (size_t)(8 + a) * CHW);
#pragma unroll
            for (int b = 0; b < 4; ++b)
                v2[b] = *reinterpret_cast<const f4*>(bp + (size_t)(G2B + b) * CHW);
#pragma unroll
            for (int a = 0; a < 8; ++a)
#pragma unroll
                for (int b = 0; b < 4; ++b)
                    acc[a * 4 + b] = dot4(v1[a], v2[b], acc[a * 4 + b]);
        }
#pragma unroll
        for (int a = 0; a < 8; ++a)
#pragma unroll
            for (int b = 0; b < 4; ++b) {
                const float s = wred(acc[a * 4 + b]);
                if (lane == 0) {
                    const int G1 = 8 + a, G2 = G2B + b;
                    red[G1 * (G1 + 1) / 2 + G2] = s;
                }
            }
    }
    __syncthreads();
    if (threadIdx.x < NVAL)
        partials[(size_t)threadIdx.x * nblk + blockIdx.x] = red[threadIdx.x];
}

// Pass 2 (one block, 1024 thr): parallel partial-reduce, then wave-parallel
// register Cholesky + triangular inverse on wave 0 (lane i = row i).
__global__ __launch_bounds__(1024) void solve_k(const float* __restrict__ partials,
                                                int nblk, float* __restrict__ wm) {
    __shared__ float sm[NVAL];
    const int lane = threadIdx.x & 63;
    const int wave = threadIdx.x >> 6;
    for (int v = wave; v < NVAL; v += 16) {
        float a = 0.f;
        for (int b = lane; b < nblk; b += 64)
            a += partials[(size_t)v * nblk + b];
#pragma unroll
        for (int o = 32; o > 0; o >>= 1) a += __shfl_xor(a, o, 64);
        if (lane == 0) sm[v] = a;
    }
    __syncthreads();
    if (wave != 0) return;

    const float inv_m = 1.0f / M_ELEMS;
    const int i = lane;  // row index (valid for i<16)
    const float mu_i = (i < G16) ? sm[NPAIR + i] * inv_m : 0.f;

    float di = 0.f;
    if (i < G16) di = sm[i * (i + 1) / 2 + i] * inv_m - mu_i * mu_i + EPSV;
    float tr = di;
#pragma unroll
    for (int o = 32; o > 0; o >>= 1) tr += __shfl_xor(tr, o, 64);
    const float rtr = 1.0f / tr;

    float A[G16];
#pragma unroll
    for (int j = 0; j < G16; ++j) {
        const float mu_j = sm[NPAIR + j] * inv_m;
        const int idx = (i >= j) ? (i * (i + 1) / 2 + j) : (j * (j + 1) / 2 + i);
        float v = (i < G16) ? sm[idx] * inv_m : 0.f;
        v = v - mu_i * mu_j + ((i == j) ? EPSV : 0.f);
        A[j] = v * rtr;
    }

    float Lr[G16];
    float dinv = 0.f;
#pragma unroll
    for (int j = 0; j < G16; ++j) {
        float s = A[j];
#pragma unroll
        for (int k = 0; k < j; ++k)
            s -= Lr[k] * __shfl(Lr[k], j, 64);
        const float djj = __shfl(s, j, 64);
        const float d = sqrtf(djj);
        const float inv = 1.0f / d;
        float lij = (i == j) ? d : s * inv;
        if (i < j) lij = 0.f;
        Lr[j] = lij;
        if (i == j) dinv = inv;
    }

    float Wc[G16];
#pragma unroll
    for (int r = 0; r < G16; ++r) {
        float s = (lane == r) ? 1.f : 0.f;
#pragma unroll
        for (int k = 0; k < r; ++k)
            s -= __shfl(Lr[k], r, 64) * Wc[k];
        Wc[r] = s * __shfl(dinv, r, 64);
    }
    if (lane < G16) {
#pragma unroll
        for (int r = 0; r < G16; ++r)
            wm[r * G16 + lane] = Wc[r];
    }
}

// Pass 3: out[g,:] = sum_{g2<=g} wm[g][g2] * x[g2,:]
// Exactly ONE float4 chunk per thread: no loop interleaving, no spills.
// NT stores keep `out` from evicting L3-resident x.
__global__ __launch_bounds__(256, 4) void apply_k(const float* __restrict__ x,
                                                  const float* __restrict__ wm,
                                                  float* __restrict__ out) {
    __shared__ float w[G16 * G16];
    if (threadIdx.x < G16 * G16) w[threadIdx.x] = wm[threadIdx.x];
    __syncthreads();
    const int c = blockIdx.x * 256 + threadIdx.x;
    const int n = c / J4;
    const int j4 = c - n * J4;
    const size_t base = (size_t)n * (G16 * CHW) + (size_t)j4 * 4;
    f4 v[G16];
#pragma unroll
    for (int g = 0; g < G16; ++g)
        v[g] = *reinterpret_cast<const f4*>(x + base + (size_t)g * CHW);
#pragma unroll
    for (int g = 0; g < G16; ++g) {
        f4 o = {0.f, 0.f, 0.f, 0.f};
#pragma unroll
        for (int g2 = 0; g2 <= g; ++g2) {
            const float wv = w[g * G16 + g2];
            o.x = fmaf(wv, v[g2].x, o.x);
            o.y = fmaf(wv, v[g2].y, o.y);
            o.z = fmaf(wv, v[g2].z, o.z);
            o.w = fmaf(wv, v[g2].w, o.w);
        }
        __builtin_nontemporal_store(o, reinterpret_cast<f4*>(out + base + (size_t)g * CHW));
    }
}

extern "C" void kernel_launch(void* const* d_in, const int* in_sizes, int n_in,
                              void* d_out, int out_size, void* d_ws, size_t ws_size,
                              hipStream_t stream) {
    const float* x = (const float*)d_in[0];
    float* out = (float*)d_out;
    float* wm = (float*)d_ws;                 // first 256 floats
    float* partials = (float*)d_ws + 256;     // NVAL * nblk floats

    int nblk = NBLK_MAX;
    const size_t avail = (ws_size / 4 > 256) ? ((ws_size / 4 - 256) / NVAL) : 1;
    if ((size_t)nblk > avail) nblk = (int)avail;
    if (nblk < 1) nblk = 1;

    gram_k<<<nblk, 256, 0, stream>>>(x, partials, nblk);
    solve_k<<<1, 1024, 0, stream>>>(partials, nblk, wm);
    apply_k<<<NCHUNK / 256, 256, 0, stream>>>(x, wm, out);
}